// Round 3
// 14717.822 us; speedup vs baseline: 1.5870x; 1.5870x over previous
//
#include <hip/hip_runtime.h>

// ULSTM layer: S=1024, B=32, IN=1024, H=1024
//  R5: fence-free coherent exchange, race fixed for real.
//  R3/R4 bug: gridbar's flag release is performed by wave 0 only, and
//  s_waitcnt vmcnt(0) is PER-WAVE — wave 2's v-publish (and wave 1's
//  h-publish) sc0+sc1 write-through stores (~600-900cy to the IF$) were
//  still in flight when the flag became visible grid-wide. Remote blocks
//  read stale v/h nondeterministically. Fix: ALL threads drain their own
//  vmcnt before arriving at the barrier, so every coherent data store has
//  completed at the coherence point before the flag release.

typedef unsigned short u16;
typedef __attribute__((ext_vector_type(4))) float f32x4;
typedef __attribute__((ext_vector_type(8))) short s16x8;     // 8 bf16 (MFMA A/B frag)
typedef __attribute__((ext_vector_type(8))) unsigned short u16x8;

#define SEQ   1024
#define BATCH 32
#define HDIM  1024
#define GBLK  64          // persistent blocks; each owns 16 hidden cols

__device__ __forceinline__ u16 f2bf(float f) {
    unsigned u = __builtin_bit_cast(unsigned, f);
    return (u16)((u + 0x7FFFu + ((u >> 16) & 1u)) >> 16);   // RNE
}
__device__ __forceinline__ float bf2f(u16 h) {
    return __builtin_bit_cast(float, (unsigned)h << 16);
}

// ---- coherent (L1+L2-bypassing) accessors for cross-block state -------------
// sc0 sc1 loads/stores are served at the IF$ (device coherence point), same as
// the relaxed agent atomics the flag poll uses. Data published this way is
// visible without any acquire fence, so L2 never gets invalidated and the
// weight matrices stay L2-resident across all 1024 timesteps.
__device__ __forceinline__ u16x8 gload_cc(const u16* p) {
    u16x8 v;
    asm volatile("global_load_dwordx4 %0, %1, off sc0 sc1" : "=&v"(v) : "v"(p));
    return v;
}
__device__ __forceinline__ void vmwait0() {
    asm volatile("s_waitcnt vmcnt(0)" ::: "memory");
    __builtin_amdgcn_sched_barrier(0);       // rule #18: pin uses after the wait
}
__device__ __forceinline__ void gstore_cc(u16* p, u16 d) {
    unsigned x = d;
    asm volatile("global_store_short %0, %1, off sc0 sc1" :: "v"(p), "v"(x) : "memory");
}

// ---------------------------------------------------------------- prep kernels
// permuted column p: g = p/80, r = p%80, gate = r>>4 (0..4 = i,o,z,f,u), j = r&15
// hidden index n = 16g + j; original 5H col = gate<4 ? gate*H+n : 4H+n
__global__ void prep_w0(const float* __restrict__ W, const float* __restrict__ b_ux,
                        const float* __restrict__ b_h, const float* __restrict__ b_um,
                        u16* __restrict__ W0p, float* __restrict__ biasp) {
    int p = blockIdx.x;                       // 5120
    int g = p / 80, r = p % 80, gate = r >> 4, j = r & 15;
    int n = 16 * g + j;
    int c = (gate < 4) ? gate * 1024 + n : 4096 + n;
    for (int k = threadIdx.x; k < 1024; k += 256)
        W0p[(long)p * 1024 + k] = f2bf(W[(long)k * 5120 + c]);
    if (threadIdx.x == 0)
        biasp[p] = b_ux[c] + ((gate < 4) ? b_h[gate * 1024 + n] : b_um[n]);
}

__global__ void prep_w1(const float* __restrict__ W, u16* __restrict__ W1p) {
    int qq = blockIdx.x;                      // 4096
    int g = qq >> 6, r = qq & 63, gate = r >> 4, j = r & 15;
    int n = 16 * g + j;
    int c = gate * 1024 + n;
    for (int k = threadIdx.x; k < 1024; k += 256)
        W1p[(long)qq * 1024 + k] = f2bf(W[(long)k * 4096 + c]);
}

__global__ void prep_w2(const float* __restrict__ W, u16* __restrict__ W2p) {
    int n = blockIdx.x;                       // 1024
    for (int k = threadIdx.x; k < 1024; k += 256)
        W2p[(long)n * 1024 + k] = f2bf(W[(long)k * 1024 + n]);
}

// ---------------------------------------------------------- input projection
// C = X(32768x1024) @ W0p^T, + biasp; output re-laid out per (g,t) slice:
// Yp[(((g*1024 + s)*32 + b)*80 + r] so ulstm_rec block g reads a contiguous
// 5120B slice per timestep.
__global__ void __launch_bounds__(256) gemm_in(const float* __restrict__ X,
                                               const u16* __restrict__ W0p,
                                               const float* __restrict__ biasp,
                                               u16* __restrict__ Yp) {
    __shared__ u16 As[128 * 40];
    __shared__ u16 Bs[64 * 40];
    const int tid = threadIdx.x, lane = tid & 63, w = tid >> 6;
    const int m = lane & 15, q = lane >> 4;
    const int m0 = blockIdx.y * 128, n0 = blockIdx.x * 64;

    f32x4 acc[2][4];
#pragma unroll
    for (int a = 0; a < 2; ++a)
#pragma unroll
        for (int b = 0; b < 4; ++b) acc[a][b] = (f32x4){0.f, 0.f, 0.f, 0.f};

    const int ar = tid >> 1, as = (tid & 1) * 16;
    const int br = tid >> 2, bs = (tid & 3) * 8;

    for (int k0 = 0; k0 < 1024; k0 += 32) {
        const float* xp = X + (long)(m0 + ar) * 1024 + k0 + as;
        float4 x0 = *(const float4*)(xp);
        float4 x1 = *(const float4*)(xp + 4);
        float4 x2 = *(const float4*)(xp + 8);
        float4 x3 = *(const float4*)(xp + 12);
        u16x8 pa, pb;
        pa[0]=f2bf(x0.x); pa[1]=f2bf(x0.y); pa[2]=f2bf(x0.z); pa[3]=f2bf(x0.w);
        pa[4]=f2bf(x1.x); pa[5]=f2bf(x1.y); pa[6]=f2bf(x1.z); pa[7]=f2bf(x1.w);
        pb[0]=f2bf(x2.x); pb[1]=f2bf(x2.y); pb[2]=f2bf(x2.z); pb[3]=f2bf(x2.w);
        pb[4]=f2bf(x3.x); pb[5]=f2bf(x3.y); pb[6]=f2bf(x3.z); pb[7]=f2bf(x3.w);
        u16x8 bv = *(const u16x8*)(W0p + (long)(n0 + br) * 1024 + k0 + bs);

        *(u16x8*)&As[ar * 40 + as]     = pa;
        *(u16x8*)&As[ar * 40 + as + 8] = pb;
        *(u16x8*)&Bs[br * 40 + bs]     = bv;
        __syncthreads();

        s16x8 a0 = *(const s16x8*)&As[(w * 32 + m) * 40 + q * 8];
        s16x8 a1 = *(const s16x8*)&As[(w * 32 + 16 + m) * 40 + q * 8];
#pragma unroll
        for (int nt = 0; nt < 4; ++nt) {
            s16x8 b = *(const s16x8*)&Bs[(nt * 16 + m) * 40 + q * 8];
            acc[0][nt] = __builtin_amdgcn_mfma_f32_16x16x32_bf16(a0, b, acc[0][nt], 0, 0, 0);
            acc[1][nt] = __builtin_amdgcn_mfma_f32_16x16x32_bf16(a1, b, acc[1][nt], 0, 0, 0);
        }
        __syncthreads();
    }
#pragma unroll
    for (int mt = 0; mt < 2; ++mt)
#pragma unroll
        for (int nt = 0; nt < 4; ++nt) {
            int p = n0 + nt * 16 + m;
            int gg = p / 80, rr = p - gg * 80;
            float bias = biasp[p];
#pragma unroll
            for (int r = 0; r < 4; ++r) {
                int row = m0 + w * 32 + mt * 16 + q * 4 + r;
                int s = row >> 5, b = row & 31;
                Yp[(((long)gg * 1024 + s) * 32 + b) * 80 + rr] = f2bf(acc[mt][nt][r] + bias);
            }
        }
}

// -------------------------------------------------------------- grid barrier
// flags: 64 slots, 128B apart. EVERY thread first drains its own vmcnt so all
// coherent publishes (wave 1's h, wave 2's v — not covered by wave 0's
// release!) are complete at the coherence point. Then wave 0 releases the
// block's flag; wave0's 64 lanes poll all flags + ballot with s_sleep backoff.
// NO acquire fence on exit: consumers read remote data only through sc0 sc1
// ops, so the L2 (holding W1p/W2p) is never invalidated.
__device__ __forceinline__ void gridbar(unsigned* flags, unsigned phase, int g) {
    asm volatile("s_waitcnt vmcnt(0)" ::: "memory");   // per-wave store drain
    __syncthreads();
    if (threadIdx.x < 64) {
        if (threadIdx.x == 0)
            __hip_atomic_store(&flags[g * 32], phase, __ATOMIC_RELEASE,
                               __HIP_MEMORY_SCOPE_AGENT);
        for (;;) {
            unsigned v = __hip_atomic_load(&flags[threadIdx.x * 32], __ATOMIC_RELAXED,
                                           __HIP_MEMORY_SCOPE_AGENT);
            if (__ballot(v >= phase) == ~0ull) break;
            __builtin_amdgcn_s_sleep(1);
        }
    }
    __syncthreads();
}

// ------------------------------------------------------------- recurrence
__global__ void __launch_bounds__(256, 1) ulstm_rec(const u16* __restrict__ W1p,
                                                    const u16* __restrict__ W2p,
                                                    const u16* __restrict__ Yp,
                                                    u16* h_buf, u16* v_buf,
                                                    float* __restrict__ out,
                                                    unsigned* flags) {
    __shared__ u16 stage[32 * 1032];        // h (phase A) / v (phase B)
    __shared__ u16 ys[2][2560];             // double-buffered Y slice (32x80)
    __shared__ float gl[4][32][17];         // i,o,z,f (padded)
    __shared__ float c_l[32][17], ct_l[32][17];

    const int g = blockIdx.x, tid = threadIdx.x, lane = tid & 63, w = tid >> 6;
    const int m = lane & 15, q = lane >> 4;

    for (int i = tid; i < 512; i += 256) {
        int row = i >> 4, col = i & 15;
        c_l[row][col] = 0.f; ct_l[row][col] = 0.f;
        // cache-bypassing so h_buf lines are never dirty in any XCD's L2
        gstore_cc(&h_buf[row * 1024 + g * 16 + col], (u16)0);
    }
    {   // prefetch Y slice for t=0 (nontemporal: stream, don't pollute L2)
        const u16x8* src = (const u16x8*)(Yp + (long)g * 1024 * 2560);
        for (int i = tid; i < 320; i += 256)
            *(u16x8*)&ys[0][i * 8] = __builtin_nontemporal_load(&src[i]);
    }
    unsigned phase = 1;
    gridbar(flags, phase, g);

    for (int t = 0; t < SEQ; ++t) {
        const u16* ysb = ys[t & 1];

        // ---- stage h: issue 16 coherent 16B loads/thread (deep MLP), then
        // overlap the Y(t+1) prefetch under their latency, then drain+write.
        u16x8 hreg[16];
#pragma unroll
        for (int j = 0; j < 16; ++j) {
            int cch = tid + j * 256;
            int r = cch >> 7, kc = cch & 127;
            hreg[j] = gload_cc(&h_buf[r * 1024 + kc * 8]);
        }
        if (t + 1 < SEQ) {
            const u16x8* src = (const u16x8*)(Yp + ((long)g * 1024 + t + 1) * 2560);
            u16* dst = ys[(t + 1) & 1];
            for (int i = tid; i < 320; i += 256)
                *(u16x8*)&dst[i * 8] = __builtin_nontemporal_load(&src[i]);
        }
        vmwait0();
#pragma unroll
        for (int j = 0; j < 16; ++j) {
            int cch = tid + j * 256;
            int r = cch >> 7, kc = cch & 127;
            *(u16x8*)&stage[r * 1032 + kc * 8] = hreg[j];
        }
        __syncthreads();

        // ---- gemm1: preact[32 x 16] for gate w (weights are L2-hot)
        f32x4 acc0 = (f32x4){0.f,0.f,0.f,0.f}, acc1 = (f32x4){0.f,0.f,0.f,0.f};
        {
            const int brow = g * 64 + w * 16 + m;
            const u16* wp = W1p + (long)brow * 1024;
#pragma unroll 8
            for (int kc = 0; kc < 32; ++kc) {
                int k0 = kc * 32 + q * 8;
                s16x8 a0 = *(const s16x8*)&stage[m * 1032 + k0];
                s16x8 a1 = *(const s16x8*)&stage[(16 + m) * 1032 + k0];
                s16x8 b  = *(const s16x8*)&wp[k0];
                acc0 = __builtin_amdgcn_mfma_f32_16x16x32_bf16(a0, b, acc0, 0, 0, 0);
                acc1 = __builtin_amdgcn_mfma_f32_16x16x32_bf16(a1, b, acc1, 0, 0, 0);
            }
        }
#pragma unroll
        for (int r = 0; r < 4; ++r) {
            int row0 = q * 4 + r, row1 = row0 + 16;
            float p0 = acc0[r] + bf2f(ysb[row0 * 80 + w * 16 + m]);
            float p1 = acc1[r] + bf2f(ysb[row1 * 80 + w * 16 + m]);
            float g0 = 1.f / (1.f + __expf(-p0));
            float g1 = 1.f / (1.f + __expf(-p1));
            gl[w][row0][m] = g0;
            gl[w][row1][m] = g1;
            if (w == 2) {       // z-gate: publish v = sigmoid(z) * tanh(c_prev)
                gstore_cc(&v_buf[row0 * 1024 + g * 16 + m], f2bf(g0 * ct_l[row0][m]));
                gstore_cc(&v_buf[row1 * 1024 + g * 16 + m], f2bf(g1 * ct_l[row1][m]));
            }
        }
        gridbar(flags, ++phase, g);         // v published grid-wide (drained)

        // ---- stage v into LDS (same batched coherent-load pattern)
        u16x8 vreg[16];
#pragma unroll
        for (int j = 0; j < 16; ++j) {
            int cch = tid + j * 256;
            int r = cch >> 7, kc = cch & 127;
            vreg[j] = gload_cc(&v_buf[r * 1024 + kc * 8]);
        }
        vmwait0();
#pragma unroll
        for (int j = 0; j < 16; ++j) {
            int cch = tid + j * 256;
            int r = cch >> 7, kc = cch & 127;
            *(u16x8*)&stage[r * 1032 + kc * 8] = vreg[j];
        }
        __syncthreads();

        // ---- gemm2 + state update (waves 0,1)
        if (w < 2) {
            f32x4 acc = (f32x4){0.f,0.f,0.f,0.f};
            const u16* wp = W2p + (long)(g * 16 + m) * 1024;
#pragma unroll 8
            for (int kc = 0; kc < 32; ++kc) {
                int k0 = kc * 32 + q * 8;
                s16x8 a = *(const s16x8*)&stage[(w * 16 + m) * 1032 + k0];
                s16x8 b = *(const s16x8*)&wp[k0];
                acc = __builtin_amdgcn_mfma_f32_16x16x32_bf16(a, b, acc, 0, 0, 0);
            }
#pragma unroll
            for (int r = 0; r < 4; ++r) {
                int row = w * 16 + q * 4 + r;
                float up = acc[r] + bf2f(ysb[row * 80 + 64 + m]);
                float eu = __expf(2.f * up);
                float u = 1.f - 2.f / (eu + 1.f);           // tanh
                float iv = gl[0][row][m], ov = gl[1][row][m], fv = gl[3][row][m];
                float cv = c_l[row][m];
                float cn = iv * u + fv * cv;
                float ec = __expf(2.f * cn);
                float ctn = 1.f - 2.f / (ec + 1.f);
                float hn = ov * ctn;
                c_l[row][m] = cn;
                ct_l[row][m] = ctn;
                gstore_cc(&h_buf[row * 1024 + g * 16 + m], f2bf(hn));
                __builtin_nontemporal_store(hn, &out[(long)(t * 32 + row) * 1024 + g * 16 + m]);
                if (t == SEQ - 1) {
                    out[33554432l + row * 1024 + g * 16 + m] = hn;          // h_n
                    out[33554432l + 32768 + row * 1024 + g * 16 + m] = cn;  // c_n
                }
            }
        }
        gridbar(flags, ++phase, g);         // h published grid-wide (drained)
    }
}

// ---------------------------------------------------------------------- host
extern "C" void kernel_launch(void* const* d_in, const int* in_sizes, int n_in,
                              void* d_out, int out_size, void* d_ws, size_t ws_size,
                              hipStream_t stream) {
    (void)in_sizes; (void)n_in; (void)out_size; (void)ws_size;
    const float* X  = (const float*)d_in[0];
    const float* W0 = (const float*)d_in[1];
    const float* b0 = (const float*)d_in[2];
    const float* W1 = (const float*)d_in[3];
    const float* b1 = (const float*)d_in[4];
    const float* W2 = (const float*)d_in[5];
    const float* b2 = (const float*)d_in[6];
    float* out = (float*)d_out;
    char* ws = (char*)d_ws;

    u16*   Yp    = (u16*)(ws);                      // 335,544,320 B
    u16*   W0p   = (u16*)(ws + 335544320l);         // 10,485,760
    u16*   W1p   = (u16*)(ws + 346030080l);         // 8,388,608
    u16*   W2p   = (u16*)(ws + 354418688l);         // 2,097,152
    float* biasp = (float*)(ws + 356515840l);       // 20,480
    u16*   h_buf = (u16*)(ws + 356536320l);         // 65,536
    u16*   v_buf = (u16*)(ws + 356601856l);         // 65,536
    unsigned* flags = (unsigned*)(ws + 356667392l); // 8,192 (64 x 128B)

    hipMemsetAsync(flags, 0, 8192, stream);
    prep_w0<<<5120, 256, 0, stream>>>(W0, b0, b1, b2, W0p, biasp);
    prep_w1<<<4096, 256, 0, stream>>>(W1, W1p);
    prep_w2<<<1024, 256, 0, stream>>>(W2, W2p);
    gemm_in<<<dim3(80, 256), 256, 0, stream>>>(X, W0p, biasp, Yp);

    void* args[] = { (void*)&W1p, (void*)&W2p, (void*)&Yp,
                     (void*)&h_buf, (void*)&v_buf, (void*)&out, (void*)&flags };
    hipLaunchCooperativeKernel(reinterpret_cast<void*>(ulstm_rec),
                               dim3(GBLK), dim3(256), args, 0, stream);
}